// Round 13
// baseline (144.898 us; speedup 1.0000x reference)
//
#include <hip/hip_runtime.h>
#include <math.h>

#define NT 1024
#define PW 66              // padded row stride for r_s and V (cols -1..64)
#define RSZ (50 * PW)      // 3300 floats: rows 0..49
#define PSL (48 * 64)      // 3072 floats: one partial slab (core cells only)

// Pin to AGPR (unified file) — frees arch VGPRs for the hot window/temps.
#define AW(arr, idx, val) asm("v_accvgpr_write_b32 %0, %1" : "=a"(arr[idx]) : "v"(val))
#define AR(dst, arr, idx) asm("v_accvgpr_read_b32 %0, %1" : "=v"(dst) : "a"(arr[idx]))

// Two launches: chunk<15,FIRST> then chunk<14,LAST>. 256 blocks, block = half image
// (32 core rows + 16-row halo; 48 v-rows, LDS row L <-> image row vlo+L-1).
//
// Wave w: g4 = w&3 -> channels 4*g4..4*g4+3, WAVE-UNIFORM -> the 36 weights are
// scalar-loaded into SGPRs (indexed wB[o*9+t], uniform base + const offsets; NO
// local array — r11/r12 showed arrays of readfirstlane results become per-lane
// registers). band = w>>2 -> rows band*12..band*12+11; lane = column.
// Per sweep: ph1 = each wave writes its 4-ch partial max into its slab P[g4]
// (no cross-lane shuffles at all); barrier; ph2 = 3 cells/thread combine the 4
// slabs into the single window buffer V; barrier. rq[48] pinned in AGPRs.
template<int NIT, bool FIRST, bool LAST>
__global__ __launch_bounds__(NT)
void vin_chunk(const float* __restrict__ layout,
               const float* __restrict__ heatmap,
               const float* __restrict__ h_w,
               const float* __restrict__ h_b,
               const float* __restrict__ r_w,
               const float* __restrict__ q_w,
               const float* __restrict__ w,
               const float* __restrict__ fc_w,
               const int* __restrict__ S1,
               const int* __restrict__ S2,
               float* __restrict__ vg,
               float* __restrict__ out)
{
    __shared__ float S[2 * RSZ + 4 * PSL];   // 3300+3300+12288 = 18888 f = 75.5 KB
    __shared__ float rh[28];
    float* r_s = S;               // steady: r rows 0..49
    float* V   = S + RSZ;         // combined v, rows 0..49 (ring rows/cols = 0)
    float* P   = S + 2 * RSZ;     // partials: P[g4][48][64]
    float* X0  = S;               // staging aliases: 52*66 = 3432 floats each
    float* X1  = S + 3432;
    float* X2  = S + 6864;        // ends at 10296 < 18888

    const int b2   = blockIdx.x;
    const int b    = b2 >> 1;
    const int half = b2 & 1;
    const int vlo  = half ? 16 : 0;
    const int tid  = threadIdx.x;

    // zero X staging region (OOB rows/halo cols must read 0 during r-conv)
    for (int i = tid; i < 3 * 3432; i += NT) S[i] = 0.f;
    __syncthreads();

    // collapse 150-ch h-conv + 1x1 r-conv into 28 coeffs
    if (tid < 896) {
        const int coeff = tid >> 5, j = tid & 31;
        float s = 0.f;
        for (int cch = j; cch < 150; cch += 32)
            s += r_w[cch] * ((coeff < 27) ? h_w[cch * 27 + coeff] : h_b[cch]);
        s += __shfl_xor(s, 1, 32);  s += __shfl_xor(s, 2, 32);
        s += __shfl_xor(s, 4, 32);  s += __shfl_xor(s, 8, 32);
        s += __shfl_xor(s, 16, 32);
        if (j == 0) rh[coeff] = s;
    }
    // stage X rows M=0..51 <-> image rows vlo-2..vlo+49
    const float* X0g = layout  + (size_t)b * 2 * 4096;
    const float* X1g = X0g + 4096;
    const float* X2g = heatmap + (size_t)b * 4096;
    for (int i = tid; i < 52 * 64; i += NT) {
        const int M = i >> 6, col = i & 63;
        const int ir = vlo - 2 + M;
        if (ir >= 0 && ir < 64) {
            const int s = ir * 64 + col, d = M * PW + col + 1;
            X0[d] = X0g[s]; X1[d] = X1g[s]; X2[d] = X2g[s];
        }
    }
    __syncthreads();  // X + rh ready

    // r rows 0..49 into registers (r row M needs X rows M..M+2)
    float rv[4];
    int   rpx[4];
    #pragma unroll
    for (int k2 = 0; k2 < 4; ++k2) {
        const int i = tid + k2 * NT;
        rpx[k2] = -1;
        if (i < 50 * 64) {
            const int row = i >> 6, col = i & 63;
            float acc = rh[27];
            #pragma unroll
            for (int dy = 0; dy < 3; ++dy)
                #pragma unroll
                for (int dx = 0; dx < 3; ++dx) {
                    const int idx = (row + dy) * PW + col + dx;
                    acc = fmaf(rh[0 * 9 + dy * 3 + dx], X0[idx], acc);
                    acc = fmaf(rh[1 * 9 + dy * 3 + dx], X1[idx], acc);
                    acc = fmaf(rh[2 * 9 + dy * 3 + dx], X2[idx], acc);
                }
            const int ir = vlo - 1 + row;
            rv[k2]  = (ir >= 0 && ir < 64) ? acc : 0.f;  // true zero padding
            rpx[k2] = row * PW + col + 1;
        }
    }
    __syncthreads();  // X consumed

    // write r; init V (ring = 0; interior = staged v or 0)
    for (int i = tid; i < RSZ; i += NT) {
        const int row = i / PW, cc = i - row * PW;
        const bool interior = (row >= 1) & (row <= 48) & (cc >= 1) & (cc <= 64);
        float v = 0.f;
        if (!FIRST && interior)
            v = vg[b * 4096 + (vlo + row - 1) * 64 + (cc - 1)];
        V[i] = v;
    }
    #pragma unroll
    for (int k2 = 0; k2 < 4; ++k2) if (rpx[k2] >= 0) r_s[rpx[k2]] = rv[k2];
    __syncthreads();  // r + V ready

    // per-lane geometry
    const int wid  = tid >> 6, lane = tid & 63;
    const int g4u  = __builtin_amdgcn_readfirstlane(wid & 3);  // uniform channel group
    const int band = wid >> 2;        // 0..3
    const int rb0  = band * 12;       // window-top V row for j=0; cells rows rb0..rb0+11
    const int c    = lane;            // column; padded cols c..c+2
    const float* qwB = q_w + g4u * 36;   // uniform base -> scalar loads
    const float* wB  = w   + g4u * 36;
    float* Pg = P + g4u * PSL;

    // rq[o*12+j] -> AGPRs; partial v0 maxes -> Pg
    float rqa[48];
    {
        float a0[3], a1[3], a2[3];
        #pragma unroll
        for (int d = 0; d < 3; ++d) {
            a0[d] = r_s[rb0 * PW + c + d];
            a1[d] = r_s[(rb0 + 1) * PW + c + d];
        }
        #pragma unroll
        for (int j = 0; j < 12; ++j) {
            #pragma unroll
            for (int d = 0; d < 3; ++d) a2[d] = r_s[(rb0 + j + 2) * PW + c + d];
            float m;
            #pragma unroll
            for (int o = 0; o < 4; ++o) {
                float q = 0.f;
                q = fmaf(qwB[o*9+0], a0[0], q); q = fmaf(qwB[o*9+1], a0[1], q); q = fmaf(qwB[o*9+2], a0[2], q);
                q = fmaf(qwB[o*9+3], a1[0], q); q = fmaf(qwB[o*9+4], a1[1], q); q = fmaf(qwB[o*9+5], a1[2], q);
                q = fmaf(qwB[o*9+6], a2[0], q); q = fmaf(qwB[o*9+7], a2[1], q); q = fmaf(qwB[o*9+8], a2[2], q);
                AW(rqa, o * 12 + j, q);
                m = (o == 0) ? q : fmaxf(m, q);
            }
            Pg[(rb0 + j) * 64 + c] = m;
            #pragma unroll
            for (int d = 0; d < 3; ++d) { a0[d] = a1[d]; a1[d] = a2[d]; }
        }
    }
    __syncthreads();  // partials ready
    if (FIRST) {
        // combine partials -> V interior (v0); skipped when V holds staged v
        #pragma unroll
        for (int k2 = 0; k2 < 3; ++k2) {
            const int idx = tid + k2 * NT;
            const int row = idx >> 6, col = idx & 63;
            const int pi = row * 64 + col;
            const float m = fmaxf(fmaxf(P[pi], P[PSL + pi]),
                                  fmaxf(P[2 * PSL + pi], P[3 * PSL + pi]));
            V[(row + 1) * PW + col + 1] = m;
        }
    }
    __syncthreads();  // V = v0 / staged v

    // NIT sweeps: ph1 (read V, write partials) | barrier | ph2 (combine -> V) | barrier
    #pragma unroll 1
    for (int it = 0; it < NIT; ++it) {
        float a0[3], a1[3], a2[3];
        #pragma unroll
        for (int d = 0; d < 3; ++d) {
            a0[d] = V[rb0 * PW + c + d];
            a1[d] = V[(rb0 + 1) * PW + c + d];
        }
        #pragma unroll
        for (int j = 0; j < 12; ++j) {
            #pragma unroll
            for (int d = 0; d < 3; ++d) a2[d] = V[(rb0 + j + 2) * PW + c + d];
            float m;
            #pragma unroll
            for (int o = 0; o < 4; ++o) {
                float q;
                AR(q, rqa, o * 12 + j);
                q = fmaf(wB[o*9+0], a0[0], q); q = fmaf(wB[o*9+1], a0[1], q); q = fmaf(wB[o*9+2], a0[2], q);
                q = fmaf(wB[o*9+3], a1[0], q); q = fmaf(wB[o*9+4], a1[1], q); q = fmaf(wB[o*9+5], a1[2], q);
                q = fmaf(wB[o*9+6], a2[0], q); q = fmaf(wB[o*9+7], a2[1], q); q = fmaf(wB[o*9+8], a2[2], q);
                m = (o == 0) ? q : fmaxf(m, q);
            }
            Pg[(rb0 + j) * 64 + c] = m;
            #pragma unroll
            for (int d = 0; d < 3; ++d) { a0[d] = a1[d]; a1[d] = a2[d]; }
        }
        __syncthreads();
        #pragma unroll
        for (int k2 = 0; k2 < 3; ++k2) {
            const int idx = tid + k2 * NT;
            const int row = idx >> 6, col = idx & 63;
            const int pi = row * 64 + col;
            const float m = fmaxf(fmaxf(P[pi], P[PSL + pi]),
                                  fmaxf(P[2 * PSL + pi], P[3 * PSL + pi]));
            V[(row + 1) * PW + col + 1] = m;
        }
        __syncthreads();
    }

    // writeback core rows (image half*32 .. half*32+31; L = ir - vlo + 1)
    if (!LAST) {
        for (int i = tid; i < 32 * 64; i += NT) {
            const int ir = half * 32 + (i >> 6), col = i & 63;
            vg[b * 4096 + ir * 64 + col] = V[(ir - vlo + 1) * PW + col + 1];
        }
    } else {
        float* out_v = out + 1024 + (size_t)b * 4096;
        for (int i = tid; i < 32 * 64; i += NT) {
            const int ir = half * 32 + (i >> 6), col = i & 63;
            out_v[ir * 64 + col] = V[(ir - vlo + 1) * PW + col + 1];
        }
    }
    if (FIRST) {
        float* out_r = out + 1024 + (size_t)128 * 4096 + (size_t)b * 4096;
        float* out_h = out + 1024 + (size_t)256 * 4096 + (size_t)b * 4096;
        for (int i = tid; i < 32 * 64; i += NT) {
            const int ir = half * 32 + (i >> 6), col = i & 63;
            out_r[ir * 64 + col] = r_s[(ir - vlo + 1) * PW + col + 1];
            out_h[ir * 64 + col] = X2g[ir * 64 + col];
        }
    }

    if (LAST) {
        const int s1 = S1[b], s2 = S2[b];
        if ((s1 >> 5) == half && tid == 0) {
            float q16[16];
            #pragma unroll
            for (int o = 0; o < 16; ++o) {
                float acc = 0.f;
                #pragma unroll
                for (int dy = 0; dy < 3; ++dy)
                    #pragma unroll
                    for (int dx = 0; dx < 3; ++dx) {
                        const int li = (s1 + dy - vlo) * PW + s2 + dx;
                        acc = fmaf(q_w[o * 9 + dy * 3 + dx], r_s[li], acc);
                        acc = fmaf(w[o * 9 + dy * 3 + dx],  V[li],   acc);
                    }
                q16[o] = acc;
            }
            float lg[4];
            #pragma unroll
            for (int j = 0; j < 4; ++j) {
                float a = 0.f;
                #pragma unroll
                for (int o = 0; o < 16; ++o) a = fmaf(fc_w[j * 16 + o], q16[o], a);
                lg[j] = a;
            }
            const float m  = fmaxf(fmaxf(lg[0], lg[1]), fmaxf(lg[2], lg[3]));
            const float e0 = expf(lg[0] - m), e1 = expf(lg[1] - m);
            const float e2 = expf(lg[2] - m), e3 = expf(lg[3] - m);
            const float s  = e0 + e1 + e2 + e3;
            out[b * 4 + 0] = lg[0]; out[b * 4 + 1] = lg[1];
            out[b * 4 + 2] = lg[2]; out[b * 4 + 3] = lg[3];
            out[512 + b * 4 + 0] = e0 / s; out[512 + b * 4 + 1] = e1 / s;
            out[512 + b * 4 + 2] = e2 / s; out[512 + b * 4 + 3] = e3 / s;
        }
    }
}

extern "C" void kernel_launch(void* const* d_in, const int* in_sizes, int n_in,
                              void* d_out, int out_size, void* d_ws, size_t ws_size,
                              hipStream_t stream) {
    const float* layout  = (const float*)d_in[0];
    const float* heatmap = (const float*)d_in[1];
    const float* h_w     = (const float*)d_in[2];
    const float* h_b     = (const float*)d_in[3];
    const float* r_w     = (const float*)d_in[4];
    const float* q_w     = (const float*)d_in[5];
    const float* w       = (const float*)d_in[6];
    const float* fc_w    = (const float*)d_in[7];
    const int*   S1      = (const int*)d_in[8];
    const int*   S2      = (const int*)d_in[9];
    float* out = (float*)d_out;
    float* vg  = (float*)d_ws;   // 128*4096 f32 = 2 MB

    hipLaunchKernelGGL((vin_chunk<15, true,  false>), dim3(256), dim3(NT), 0, stream,
                       layout, heatmap, h_w, h_b, r_w, q_w, w, fc_w, S1, S2, vg, out);
    hipLaunchKernelGGL((vin_chunk<14, false, true>),  dim3(256), dim3(NT), 0, stream,
                       layout, heatmap, h_w, h_b, r_w, q_w, w, fc_w, S1, S2, vg, out);
}

// Round 14
// 112.192 us; speedup vs baseline: 1.2915x; 1.2915x over previous
//
#include <hip/hip_runtime.h>
#include <math.h>

#define NT 1024
#define PW 66      // padded LDS row stride
#define RR 52      // LDS buffer rows (52 X rows / 50 r rows / 48 v rows + ring)

// Pin to AGPR (unified file) — frees arch VGPRs for window/weights/temps.
#define AW(arr, idx, val) asm("v_accvgpr_write_b32 %0, %1" : "=a"(arr[idx]) : "v"(val))
#define AR(dst, arr, idx) asm("v_accvgpr_read_b32 %0, %1" : "=v"(dst) : "a"(arr[idx]))

// Two launches: chunk<15,FIRST> then chunk<14,LAST>. 256 blocks (1 per CU),
// block = half image (32 core rows + 16-row internal halo; 48 v-rows).
//
// Geometry (r10, proven correct): lane owns ONE column (c = tid&63) and THREE
// cell rows (ty = tid>>6, rows 1+3ty..3+3ty), computing ALL 16 channels
// in-lane: NO cross-lane shuffles, NO masked writes, NO window rotation.
// Weights live in LDS (staged once; broadcast ds_read per o — conflict-free,
// DS pipe overlaps VALU). r10's failure mode (per-use GLOBAL weight loads ->
// scalar-load stalls) is thereby removed. rq[48] explicitly AGPR-pinned:
// arch-VGPR live set ~35 << 64 -> no implicit AGPR shuttling of hot values.
template<int NIT, bool FIRST, bool LAST>
__global__ __launch_bounds__(NT)
void vin_chunk(const float* __restrict__ layout,
               const float* __restrict__ heatmap,
               const float* __restrict__ h_w,
               const float* __restrict__ h_b,
               const float* __restrict__ r_w,
               const float* __restrict__ q_w,
               const float* __restrict__ w,
               const float* __restrict__ fc_w,
               const int* __restrict__ S1,
               const int* __restrict__ S2,
               float* __restrict__ vg,
               float* __restrict__ out)
{
    __shared__ float rh[28];
    __shared__ float qw_s[144];      // conv weights staged in LDS (broadcast reads)
    __shared__ float wv_s[144];
    __shared__ float r_s[RR * PW];   // X0, then r   (row M <-> image row vlo-1+M)
    __shared__ float va[RR * PW];    // X1, then v ping (v row L <-> image row vlo+L-1)
    __shared__ float vb[RR * PW];    // X2, then v pong

    const int b2   = blockIdx.x;
    const int b    = b2 >> 1;
    const int half = b2 & 1;
    const int vlo  = half ? 16 : 0;
    const int tid  = threadIdx.x;

    // stage weights into LDS (once)
    if (tid < 144) qw_s[tid] = q_w[tid];
    else if (tid < 288) wv_s[tid - 144] = w[tid - 144];

    // B0: zero everything (borders must be 0)
    for (int i = tid; i < RR * PW; i += NT) { r_s[i] = 0.f; va[i] = 0.f; vb[i] = 0.f; }
    __syncthreads();

    // collapse 150-ch h-conv + 1x1 r-conv into 28 coeffs (32 threads per coeff)
    if (tid < 896) {
        const int coeff = tid >> 5, j = tid & 31;
        float s = 0.f;
        for (int c = j; c < 150; c += 32)
            s += r_w[c] * ((coeff < 27) ? h_w[c * 27 + coeff] : h_b[c]);
        s += __shfl_xor(s, 1, 32);  s += __shfl_xor(s, 2, 32);
        s += __shfl_xor(s, 4, 32);  s += __shfl_xor(s, 8, 32);
        s += __shfl_xor(s, 16, 32);
        if (j == 0) rh[coeff] = s;
    }
    // stage X rows M=0..51 <-> image rows vlo-2..vlo+49 (zero OOB kept from memset)
    const float* X0 = layout  + (size_t)b * 2 * 4096;
    const float* X1 = X0 + 4096;
    const float* X2 = heatmap + (size_t)b * 4096;
    for (int i = tid; i < RR * 64; i += NT) {
        const int M = i >> 6, col = i & 63;
        const int ir = vlo - 2 + M;
        if (ir >= 0 && ir < 64) {
            const int s = ir * 64 + col, d = M * PW + col + 1;
            r_s[d] = X0[s]; va[d] = X1[s]; vb[d] = X2[s];
        }
    }
    __syncthreads();  // B1: X + rh ready

    // r (rows 0..49) into registers; window top X-row == dest r-row
    float rv[4];
    int   rpx[4];
    #pragma unroll
    for (int k2 = 0; k2 < 4; ++k2) {
        const int i = tid + k2 * NT;
        rpx[k2] = -1;
        if (i < 50 * 64) {
            const int row = i >> 6, col = i & 63;
            float acc = rh[27];
            #pragma unroll
            for (int dy = 0; dy < 3; ++dy)
                #pragma unroll
                for (int dx = 0; dx < 3; ++dx) {
                    const int idx = (row + dy) * PW + col + dx;
                    acc = fmaf(rh[0 * 9 + dy * 3 + dx], r_s[idx], acc);
                    acc = fmaf(rh[1 * 9 + dy * 3 + dx], va[idx],  acc);
                    acc = fmaf(rh[2 * 9 + dy * 3 + dx], vb[idx],  acc);
                }
            const int ir = vlo - 1 + row;
            rv[k2]  = (ir >= 0 && ir < 64) ? acc : 0.f;  // true zero padding
            rpx[k2] = row * PW + col + 1;
        }
    }
    __syncthreads();  // B2: X consumed

    // overwrite: r -> r_s, re-zero v buffers
    for (int i = tid; i < RR * PW; i += NT) { va[i] = 0.f; vb[i] = 0.f; }
    #pragma unroll
    for (int k2 = 0; k2 < 4; ++k2) if (rpx[k2] >= 0) r_s[rpx[k2]] = rv[k2];
    __syncthreads();  // B3: r ready, v buffers zero

    // per-lane geometry: one column, three cell rows, all 16 channels in-lane
    const int c  = tid & 63;        // image col (LDS col c+1)
    const int ty = tid >> 6;        // 0..15
    const int L0 = 1 + 3 * ty;      // first owned v row (LDS); window rows 3ty..3ty+4

    // stage v (non-FIRST) rows 1..48 <- vg image rows vlo..vlo+47
    if (!FIRST) {
        for (int i = tid; i < 48 * 64; i += NT) {
            const int L = (i >> 6) + 1, col = i & 63;
            va[L * PW + col + 1] = vg[b * 4096 + (vlo + L - 1) * 64 + col];
        }
    }

    // rq[o*3+j] = conv3x3(r, q_w[o]) -> AGPRs; v0 = max_o rq if FIRST
    float rqa[48];
    {
        float rn[5][3];
        #pragma unroll
        for (int i = 0; i < 5; ++i)
            #pragma unroll
            for (int d = 0; d < 3; ++d)
                rn[i][d] = r_s[(3 * ty + i) * PW + c + d];
        float m0[3];
        #pragma unroll
        for (int o = 0; o < 16; ++o) {
            float w0 = qw_s[o*9+0], w1 = qw_s[o*9+1], w2 = qw_s[o*9+2];
            float w3 = qw_s[o*9+3], w4 = qw_s[o*9+4], w5 = qw_s[o*9+5];
            float w6 = qw_s[o*9+6], w7 = qw_s[o*9+7], w8 = qw_s[o*9+8];
            #pragma unroll
            for (int j = 0; j < 3; ++j) {
                float q = 0.f;
                q = fmaf(w0, rn[j+0][0], q); q = fmaf(w1, rn[j+0][1], q); q = fmaf(w2, rn[j+0][2], q);
                q = fmaf(w3, rn[j+1][0], q); q = fmaf(w4, rn[j+1][1], q); q = fmaf(w5, rn[j+1][2], q);
                q = fmaf(w6, rn[j+2][0], q); q = fmaf(w7, rn[j+2][1], q); q = fmaf(w8, rn[j+2][2], q);
                AW(rqa, o * 3 + j, q);
                m0[j] = (o == 0) ? q : fmaxf(m0[j], q);
            }
        }
        if (FIRST) {
            #pragma unroll
            for (int j = 0; j < 3; ++j)
                va[(L0 + j) * PW + c + 1] = m0[j];
        }
    }
    __syncthreads();  // B4: v0 / staged v ready

    // NIT sweeps: 16 channels in-lane, weights via LDS broadcast, rq via AGPR
    float* vcur = va;
    float* vnxt = vb;
    #pragma unroll 1
    for (int it = 0; it < NIT; ++it) {
        float vn[5][3];
        #pragma unroll
        for (int i = 0; i < 5; ++i)
            #pragma unroll
            for (int d = 0; d < 3; ++d)
                vn[i][d] = vcur[(3 * ty + i) * PW + c + d];
        float m[3];
        #pragma unroll
        for (int o = 0; o < 16; ++o) {
            float w0 = wv_s[o*9+0], w1 = wv_s[o*9+1], w2 = wv_s[o*9+2];
            float w3 = wv_s[o*9+3], w4 = wv_s[o*9+4], w5 = wv_s[o*9+5];
            float w6 = wv_s[o*9+6], w7 = wv_s[o*9+7], w8 = wv_s[o*9+8];
            #pragma unroll
            for (int j = 0; j < 3; ++j) {
                float q;
                AR(q, rqa, o * 3 + j);
                q = fmaf(w0, vn[j+0][0], q); q = fmaf(w1, vn[j+0][1], q); q = fmaf(w2, vn[j+0][2], q);
                q = fmaf(w3, vn[j+1][0], q); q = fmaf(w4, vn[j+1][1], q); q = fmaf(w5, vn[j+1][2], q);
                q = fmaf(w6, vn[j+2][0], q); q = fmaf(w7, vn[j+2][1], q); q = fmaf(w8, vn[j+2][2], q);
                m[j] = (o == 0) ? q : fmaxf(m[j], q);
            }
        }
        #pragma unroll
        for (int j = 0; j < 3; ++j)
            vnxt[(L0 + j) * PW + c + 1] = m[j];
        __syncthreads();
        float* t = vcur; vcur = vnxt; vnxt = t;
    }

    // writeback core rows (image half*32 .. half*32+31; L = ir - vlo + 1)
    if (!LAST) {
        for (int i = tid; i < 32 * 64; i += NT) {
            const int ir = half * 32 + (i >> 6), col = i & 63;
            vg[b * 4096 + ir * 64 + col] = vcur[(ir - vlo + 1) * PW + col + 1];
        }
    } else {
        float* out_v = out + 1024 + (size_t)b * 4096;
        for (int i = tid; i < 32 * 64; i += NT) {
            const int ir = half * 32 + (i >> 6), col = i & 63;
            out_v[ir * 64 + col] = vcur[(ir - vlo + 1) * PW + col + 1];
        }
    }
    if (FIRST) {
        float* out_r = out + 1024 + (size_t)128 * 4096 + (size_t)b * 4096;
        float* out_h = out + 1024 + (size_t)256 * 4096 + (size_t)b * 4096;
        for (int i = tid; i < 32 * 64; i += NT) {
            const int ir = half * 32 + (i >> 6), col = i & 63;
            out_r[ir * 64 + col] = r_s[(ir - vlo + 1) * PW + col + 1];
            out_h[ir * 64 + col] = X2[ir * 64 + col];
        }
    }

    if (LAST) {
        const int s1 = S1[b], s2 = S2[b];
        if ((s1 >> 5) == half && tid == 0) {
            float q16[16];
            #pragma unroll
            for (int o = 0; o < 16; ++o) {
                float acc = 0.f;
                #pragma unroll
                for (int dy = 0; dy < 3; ++dy)
                    #pragma unroll
                    for (int dx = 0; dx < 3; ++dx) {
                        const int li = (s1 + dy - vlo) * PW + s2 + dx;
                        acc = fmaf(qw_s[o * 9 + dy * 3 + dx], r_s[li], acc);
                        acc = fmaf(wv_s[o * 9 + dy * 3 + dx], vcur[li], acc);
                    }
                q16[o] = acc;
            }
            float lg[4];
            #pragma unroll
            for (int j = 0; j < 4; ++j) {
                float a = 0.f;
                #pragma unroll
                for (int o = 0; o < 16; ++o) a = fmaf(fc_w[j * 16 + o], q16[o], a);
                lg[j] = a;
            }
            const float m  = fmaxf(fmaxf(lg[0], lg[1]), fmaxf(lg[2], lg[3]));
            const float e0 = expf(lg[0] - m), e1 = expf(lg[1] - m);
            const float e2 = expf(lg[2] - m), e3 = expf(lg[3] - m);
            const float s  = e0 + e1 + e2 + e3;
            out[b * 4 + 0] = lg[0]; out[b * 4 + 1] = lg[1];
            out[b * 4 + 2] = lg[2]; out[b * 4 + 3] = lg[3];
            out[512 + b * 4 + 0] = e0 / s; out[512 + b * 4 + 1] = e1 / s;
            out[512 + b * 4 + 2] = e2 / s; out[512 + b * 4 + 3] = e3 / s;
        }
    }
}

extern "C" void kernel_launch(void* const* d_in, const int* in_sizes, int n_in,
                              void* d_out, int out_size, void* d_ws, size_t ws_size,
                              hipStream_t stream) {
    const float* layout  = (const float*)d_in[0];
    const float* heatmap = (const float*)d_in[1];
    const float* h_w     = (const float*)d_in[2];
    const float* h_b     = (const float*)d_in[3];
    const float* r_w     = (const float*)d_in[4];
    const float* q_w     = (const float*)d_in[5];
    const float* w       = (const float*)d_in[6];
    const float* fc_w    = (const float*)d_in[7];
    const int*   S1      = (const int*)d_in[8];
    const int*   S2      = (const int*)d_in[9];
    float* out = (float*)d_out;
    float* vg  = (float*)d_ws;   // 128*4096 f32 = 2 MB

    hipLaunchKernelGGL((vin_chunk<15, true,  false>), dim3(256), dim3(NT), 0, stream,
                       layout, heatmap, h_w, h_b, r_w, q_w, w, fc_w, S1, S2, vg, out);
    hipLaunchKernelGGL((vin_chunk<14, false, true>),  dim3(256), dim3(NT), 0, stream,
                       layout, heatmap, h_w, h_b, r_w, q_w, w, fc_w, S1, S2, vg, out);
}

// Round 15
// 105.532 us; speedup vs baseline: 1.3730x; 1.0631x over previous
//
#include <hip/hip_runtime.h>
#include <math.h>

#define NT 1024
#define PW 66      // padded LDS row stride
#define RR 52      // LDS buffer rows (52 X rows / 50 r rows / 48 v rows + ring)

// Pin to AGPR (unified file) — frees arch VGPRs for window/weights/temps.
#define AW(arr, idx, val) asm("v_accvgpr_write_b32 %0, %1" : "=a"(arr[idx]) : "v"(val))
#define AR(dst, arr, idx) asm("v_accvgpr_read_b32 %0, %1" : "=v"(dst) : "a"(arr[idx]))

// Two launches: chunk<15,FIRST> then chunk<14,LAST>. 256 blocks (1 per CU),
// block = half image (32 core rows + 16-row internal halo; 48 v-rows).
// Geometry (r14, best): lane owns ONE column (c=tid&63) and THREE cell rows
// (ty=tid>>6), all 16 channels in-lane — no shuffles, no masked writes.
// r15 deltas: (1) weights padded to 12 f/channel in LDS -> 2x ds_read_b128 +
// 1x b32 per channel (weight DS ops 144->48 per lane-sweep; DS pipe was ~50%
// of sweep cycles); (2) border-only LDS zeroing (interiors always overwritten).
template<int NIT, bool FIRST, bool LAST>
__global__ __launch_bounds__(NT)
void vin_chunk(const float* __restrict__ layout,
               const float* __restrict__ heatmap,
               const float* __restrict__ h_w,
               const float* __restrict__ h_b,
               const float* __restrict__ r_w,
               const float* __restrict__ q_w,
               const float* __restrict__ w,
               const float* __restrict__ fc_w,
               const int* __restrict__ S1,
               const int* __restrict__ S2,
               float* __restrict__ vg,
               float* __restrict__ out)
{
    __shared__ float rh[28];
    __shared__ alignas(16) float qw_s[192];   // 16 ch x 12 (9 used + 3 pad)
    __shared__ alignas(16) float wv_s[192];
    __shared__ float r_s[RR * PW];   // X0, then r   (row M <-> image row vlo-1+M)
    __shared__ float va[RR * PW];    // X1, then v ping (v row L <-> image row vlo+L-1)
    __shared__ float vb[RR * PW];    // X2, then v pong

    const int b2   = blockIdx.x;
    const int b    = b2 >> 1;
    const int half = b2 & 1;
    const int vlo  = half ? 16 : 0;
    const int tid  = threadIdx.x;

    // stage weights into LDS, padded to 12/channel (pads zeroed, never used)
    if (tid < 192) {
        const int o = tid / 12, t = tid - o * 12;
        qw_s[tid] = (t < 9) ? q_w[o * 9 + t] : 0.f;
    } else if (tid < 384) {
        const int i2 = tid - 192;
        const int o = i2 / 12, t = i2 - o * 12;
        wv_s[i2] = (t < 9) ? w[o * 9 + t] : 0.f;
    }

    // B0: border-only zero (rows 0,1,50,51 + cols 0,65) — interiors are
    // always overwritten before being read.
    for (int i = tid; i < 4 * PW; i += NT) {
        const int rr = (i < 2 * PW) ? (i / PW) : (48 + i / PW);  // 0,1,50,51
        const int cc = i % PW;
        const int idx = rr * PW + cc;
        r_s[idx] = 0.f; va[idx] = 0.f; vb[idx] = 0.f;
    }
    for (int i = tid; i < 2 * RR; i += NT) {
        const int rr = i >> 1, cc = (i & 1) ? (PW - 1) : 0;
        const int idx = rr * PW + cc;
        r_s[idx] = 0.f; va[idx] = 0.f; vb[idx] = 0.f;
    }
    __syncthreads();

    // collapse 150-ch h-conv + 1x1 r-conv into 28 coeffs (32 threads per coeff)
    if (tid < 896) {
        const int coeff = tid >> 5, j = tid & 31;
        float s = 0.f;
        for (int c = j; c < 150; c += 32)
            s += r_w[c] * ((coeff < 27) ? h_w[c * 27 + coeff] : h_b[c]);
        s += __shfl_xor(s, 1, 32);  s += __shfl_xor(s, 2, 32);
        s += __shfl_xor(s, 4, 32);  s += __shfl_xor(s, 8, 32);
        s += __shfl_xor(s, 16, 32);
        if (j == 0) rh[coeff] = s;
    }
    // stage X rows M=0..51 <-> image rows vlo-2..vlo+49 (OOB rows stay zero)
    const float* X0 = layout  + (size_t)b * 2 * 4096;
    const float* X1 = X0 + 4096;
    const float* X2 = heatmap + (size_t)b * 4096;
    for (int i = tid; i < RR * 64; i += NT) {
        const int M = i >> 6, col = i & 63;
        const int ir = vlo - 2 + M;
        if (ir >= 0 && ir < 64) {
            const int s = ir * 64 + col, d = M * PW + col + 1;
            r_s[d] = X0[s]; va[d] = X1[s]; vb[d] = X2[s];
        }
    }
    __syncthreads();  // B1: X + rh + weights ready

    // r (rows 0..49) into registers; window top X-row == dest r-row
    float rv[4];
    int   rpx[4];
    #pragma unroll
    for (int k2 = 0; k2 < 4; ++k2) {
        const int i = tid + k2 * NT;
        rpx[k2] = -1;
        if (i < 50 * 64) {
            const int row = i >> 6, col = i & 63;
            float acc = rh[27];
            #pragma unroll
            for (int dy = 0; dy < 3; ++dy)
                #pragma unroll
                for (int dx = 0; dx < 3; ++dx) {
                    const int idx = (row + dy) * PW + col + dx;
                    acc = fmaf(rh[0 * 9 + dy * 3 + dx], r_s[idx], acc);
                    acc = fmaf(rh[1 * 9 + dy * 3 + dx], va[idx],  acc);
                    acc = fmaf(rh[2 * 9 + dy * 3 + dx], vb[idx],  acc);
                }
            const int ir = vlo - 1 + row;
            rv[k2]  = (ir >= 0 && ir < 64) ? acc : 0.f;  // true zero padding
            rpx[k2] = row * PW + col + 1;
        }
    }
    __syncthreads();  // B2: X consumed

    // overwrite: r -> r_s; ring-zero v buffers (rows 0,49 + cols 0,65 of 1..48)
    for (int i = tid; i < 2 * PW + 96; i += NT) {
        int idx;
        if (i < 2 * PW) idx = ((i < PW) ? 0 : 49) * PW + (i % PW);
        else { const int k = i - 2 * PW; idx = (1 + (k >> 1)) * PW + ((k & 1) ? (PW - 1) : 0); }
        va[idx] = 0.f; vb[idx] = 0.f;
    }
    #pragma unroll
    for (int k2 = 0; k2 < 4; ++k2) if (rpx[k2] >= 0) r_s[rpx[k2]] = rv[k2];
    __syncthreads();  // B3: r ready, v rings zero

    // per-lane geometry: one column, three cell rows, all 16 channels in-lane
    const int c  = tid & 63;        // image col (LDS col c+1)
    const int ty = tid >> 6;        // 0..15
    const int L0 = 1 + 3 * ty;      // first owned v row (LDS); window rows 3ty..3ty+4

    // stage v (non-FIRST) rows 1..48 <- vg image rows vlo..vlo+47
    if (!FIRST) {
        for (int i = tid; i < 48 * 64; i += NT) {
            const int L = (i >> 6) + 1, col = i & 63;
            va[L * PW + col + 1] = vg[b * 4096 + (vlo + L - 1) * 64 + col];
        }
    }

    // rq[o*3+j] = conv3x3(r, q_w[o]) -> AGPRs; v0 = max_o rq if FIRST
    float rqa[48];
    {
        float rn[5][3];
        #pragma unroll
        for (int i = 0; i < 5; ++i)
            #pragma unroll
            for (int d = 0; d < 3; ++d)
                rn[i][d] = r_s[(3 * ty + i) * PW + c + d];
        float m0[3];
        #pragma unroll
        for (int o = 0; o < 16; ++o) {
            const float4 wa = *reinterpret_cast<const float4*>(qw_s + o * 12);
            const float4 wb = *reinterpret_cast<const float4*>(qw_s + o * 12 + 4);
            const float  w8 = qw_s[o * 12 + 8];
            #pragma unroll
            for (int j = 0; j < 3; ++j) {
                float q = 0.f;
                q = fmaf(wa.x, rn[j+0][0], q); q = fmaf(wa.y, rn[j+0][1], q); q = fmaf(wa.z, rn[j+0][2], q);
                q = fmaf(wa.w, rn[j+1][0], q); q = fmaf(wb.x, rn[j+1][1], q); q = fmaf(wb.y, rn[j+1][2], q);
                q = fmaf(wb.z, rn[j+2][0], q); q = fmaf(wb.w, rn[j+2][1], q); q = fmaf(w8,   rn[j+2][2], q);
                AW(rqa, o * 3 + j, q);
                m0[j] = (o == 0) ? q : fmaxf(m0[j], q);
            }
        }
        if (FIRST) {
            #pragma unroll
            for (int j = 0; j < 3; ++j)
                va[(L0 + j) * PW + c + 1] = m0[j];
        }
    }
    __syncthreads();  // B4: v0 / staged v ready

    // NIT sweeps: 16 channels in-lane, weights via 16B LDS reads, rq via AGPR
    float* vcur = va;
    float* vnxt = vb;
    #pragma unroll 1
    for (int it = 0; it < NIT; ++it) {
        float vn[5][3];
        #pragma unroll
        for (int i = 0; i < 5; ++i)
            #pragma unroll
            for (int d = 0; d < 3; ++d)
                vn[i][d] = vcur[(3 * ty + i) * PW + c + d];
        float m[3];
        #pragma unroll
        for (int o = 0; o < 16; ++o) {
            const float4 wa = *reinterpret_cast<const float4*>(wv_s + o * 12);
            const float4 wb = *reinterpret_cast<const float4*>(wv_s + o * 12 + 4);
            const float  w8 = wv_s[o * 12 + 8];
            #pragma unroll
            for (int j = 0; j < 3; ++j) {
                float q;
                AR(q, rqa, o * 3 + j);
                q = fmaf(wa.x, vn[j+0][0], q); q = fmaf(wa.y, vn[j+0][1], q); q = fmaf(wa.z, vn[j+0][2], q);
                q = fmaf(wa.w, vn[j+1][0], q); q = fmaf(wb.x, vn[j+1][1], q); q = fmaf(wb.y, vn[j+1][2], q);
                q = fmaf(wb.z, vn[j+2][0], q); q = fmaf(wb.w, vn[j+2][1], q); q = fmaf(w8,   vn[j+2][2], q);
                m[j] = (o == 0) ? q : fmaxf(m[j], q);
            }
        }
        #pragma unroll
        for (int j = 0; j < 3; ++j)
            vnxt[(L0 + j) * PW + c + 1] = m[j];
        __syncthreads();
        float* t = vcur; vcur = vnxt; vnxt = t;
    }

    // writeback core rows (image half*32 .. half*32+31; L = ir - vlo + 1)
    if (!LAST) {
        for (int i = tid; i < 32 * 64; i += NT) {
            const int ir = half * 32 + (i >> 6), col = i & 63;
            vg[b * 4096 + ir * 64 + col] = vcur[(ir - vlo + 1) * PW + col + 1];
        }
    } else {
        float* out_v = out + 1024 + (size_t)b * 4096;
        for (int i = tid; i < 32 * 64; i += NT) {
            const int ir = half * 32 + (i >> 6), col = i & 63;
            out_v[ir * 64 + col] = vcur[(ir - vlo + 1) * PW + col + 1];
        }
    }
    if (FIRST) {
        float* out_r = out + 1024 + (size_t)128 * 4096 + (size_t)b * 4096;
        float* out_h = out + 1024 + (size_t)256 * 4096 + (size_t)b * 4096;
        for (int i = tid; i < 32 * 64; i += NT) {
            const int ir = half * 32 + (i >> 6), col = i & 63;
            out_r[ir * 64 + col] = r_s[(ir - vlo + 1) * PW + col + 1];
            out_h[ir * 64 + col] = X2[ir * 64 + col];
        }
    }

    if (LAST) {
        const int s1 = S1[b], s2 = S2[b];
        if ((s1 >> 5) == half && tid == 0) {
            float q16[16];
            #pragma unroll
            for (int o = 0; o < 16; ++o) {
                float acc = 0.f;
                #pragma unroll
                for (int dy = 0; dy < 3; ++dy)
                    #pragma unroll
                    for (int dx = 0; dx < 3; ++dx) {
                        const int li = (s1 + dy - vlo) * PW + s2 + dx;
                        acc = fmaf(qw_s[o * 12 + dy * 3 + dx], r_s[li], acc);
                        acc = fmaf(wv_s[o * 12 + dy * 3 + dx], vcur[li], acc);
                    }
                q16[o] = acc;
            }
            float lg[4];
            #pragma unroll
            for (int j = 0; j < 4; ++j) {
                float a = 0.f;
                #pragma unroll
                for (int o = 0; o < 16; ++o) a = fmaf(fc_w[j * 16 + o], q16[o], a);
                lg[j] = a;
            }
            const float m  = fmaxf(fmaxf(lg[0], lg[1]), fmaxf(lg[2], lg[3]));
            const float e0 = expf(lg[0] - m), e1 = expf(lg[1] - m);
            const float e2 = expf(lg[2] - m), e3 = expf(lg[3] - m);
            const float s  = e0 + e1 + e2 + e3;
            out[b * 4 + 0] = lg[0]; out[b * 4 + 1] = lg[1];
            out[b * 4 + 2] = lg[2]; out[b * 4 + 3] = lg[3];
            out[512 + b * 4 + 0] = e0 / s; out[512 + b * 4 + 1] = e1 / s;
            out[512 + b * 4 + 2] = e2 / s; out[512 + b * 4 + 3] = e3 / s;
        }
    }
}

extern "C" void kernel_launch(void* const* d_in, const int* in_sizes, int n_in,
                              void* d_out, int out_size, void* d_ws, size_t ws_size,
                              hipStream_t stream) {
    const float* layout  = (const float*)d_in[0];
    const float* heatmap = (const float*)d_in[1];
    const float* h_w     = (const float*)d_in[2];
    const float* h_b     = (const float*)d_in[3];
    const float* r_w     = (const float*)d_in[4];
    const float* q_w     = (const float*)d_in[5];
    const float* w       = (const float*)d_in[6];
    const float* fc_w    = (const float*)d_in[7];
    const int*   S1      = (const int*)d_in[8];
    const int*   S2      = (const int*)d_in[9];
    float* out = (float*)d_out;
    float* vg  = (float*)d_ws;   // 128*4096 f32 = 2 MB

    hipLaunchKernelGGL((vin_chunk<15, true,  false>), dim3(256), dim3(NT), 0, stream,
                       layout, heatmap, h_w, h_b, r_w, q_w, w, fc_w, S1, S2, vg, out);
    hipLaunchKernelGGL((vin_chunk<14, false, true>),  dim3(256), dim3(NT), 0, stream,
                       layout, heatmap, h_w, h_b, r_w, q_w, w, fc_w, S1, S2, vg, out);
}